// Round 1
// baseline (279.456 us; speedup 1.0000x reference)
//
#include <hip/hip_runtime.h>

#define BATCH 2
#define SEQ 2048
#define NHEADS 16
#define DHEAD 64
#define DMODEL 1024

typedef __attribute__((ext_vector_type(8))) short bf16x8;
typedef __attribute__((ext_vector_type(4))) float f32x4;

__device__ __forceinline__ unsigned short f2b(float f) {
  union { float f; unsigned u; } a; a.f = f;
  return (unsigned short)((a.u + 0x7fffu + ((a.u >> 16) & 1u)) >> 16);
}

// ---------------------------------------------------------------------------
// Kernel 1: causal flash attention. One WG = (b, h, 64-row q tile).
// 4 waves, each owns 16 q rows. KBLK = 64. z (bf16) -> workspace.
// ---------------------------------------------------------------------------
__global__ __launch_bounds__(256) void attn_kernel(
    const float* __restrict__ qg, const float* __restrict__ kg,
    const float* __restrict__ vg, unsigned short* __restrict__ zg) {
  __shared__ unsigned short Kld[64][72];   // K tile, row-major [kpos][d]
  __shared__ unsigned short Vtld[64][72];  // V tile transposed [d][kpos]
  __shared__ unsigned short Pld[4][16][72];// per-wave P [qrow][kpos]

  const int wg = blockIdx.x;
  const int qt = wg & 31;        // q tile index (SEQ/64 = 32)
  const int bh = wg >> 5;
  const int b = bh >> 4, h = bh & 15;
  const int tid = (int)threadIdx.x;
  const int w = tid >> 6;        // wave 0..3
  const int lane = tid & 63;
  const int lg = lane >> 4;      // 16-lane group 0..3
  const int ln = lane & 15;

  // --- Q fragments in registers, scaled by 1/8 (exact). A-frag:
  // row = ln (q row w*16+ln), k = 32*c + lg*8 + i  (d dim)
  bf16x8 qf[2];
  {
    const float* qp =
        qg + ((size_t)(b * SEQ + qt * 64 + w * 16 + ln)) * DMODEL + h * DHEAD;
    #pragma unroll
    for (int c = 0; c < 2; ++c) {
      #pragma unroll
      for (int i = 0; i < 8; ++i)
        qf[c][i] = (short)f2b(qp[c * 32 + lg * 8 + i] * 0.125f);
    }
  }

  float mrow[4], lrow[4];
  f32x4 zac[4];
  #pragma unroll
  for (int i = 0; i < 4; ++i) {
    mrow[i] = -1e30f; lrow[i] = 0.f;
    zac[i][0] = 0.f; zac[i][1] = 0.f; zac[i][2] = 0.f; zac[i][3] = 0.f;
  }

  const int nkt = qt + 1;  // causal: k tiles 0..qt
  for (int kt = 0; kt < nkt; ++kt) {
    const int k0 = kt * 64;
    // ---- stage K (row-major bf16) and V^T (transposed bf16) ----
    {
      const int row = tid >> 2, quad = tid & 3;
      const size_t gbase = ((size_t)(b * SEQ + k0 + row)) * DMODEL + h * DHEAD + quad * 16;
      const float* kp = kg + gbase;
      const float* vp = vg + gbase;
      #pragma unroll
      for (int j = 0; j < 4; ++j) {
        f32x4 kv = *(const f32x4*)(kp + j * 4);
        f32x4 vv = *(const f32x4*)(vp + j * 4);
        ushort4 kb;
        kb.x = f2b(kv[0]); kb.y = f2b(kv[1]); kb.z = f2b(kv[2]); kb.w = f2b(kv[3]);
        *(ushort4*)&Kld[row][quad * 16 + j * 4] = kb;
        #pragma unroll
        for (int e = 0; e < 4; ++e)
          Vtld[quad * 16 + j * 4 + e][row] = f2b(vv[e]);
      }
    }
    __syncthreads();

    // ---- scores: S = (Q/8) * K^T, four 16x16 col-tiles ----
    f32x4 sc[4];
    #pragma unroll
    for (int t = 0; t < 4; ++t) {
      f32x4 s = {0.f, 0.f, 0.f, 0.f};
      #pragma unroll
      for (int c = 0; c < 2; ++c) {
        bf16x8 kf = *(const bf16x8*)&Kld[t * 16 + ln][c * 32 + lg * 8];
        s = __builtin_amdgcn_mfma_f32_16x16x32_bf16(qf[c], kf, s, 0, 0, 0);
      }
      sc[t] = s;
    }

    // ---- causal mask on the diagonal tile ----
    if (kt == qt) {
      #pragma unroll
      for (int t = 0; t < 4; ++t) {
        const int kloc = t * 16 + ln;
        #pragma unroll
        for (int i = 0; i < 4; ++i) {
          const int qloc = w * 16 + lg * 4 + i;
          if (kloc > qloc) sc[t][i] = -1e30f;
        }
      }
    }

    // ---- online softmax (row stats via 16-lane shuffle reduce) ----
    #pragma unroll
    for (int i = 0; i < 4; ++i) {
      float mx = fmaxf(fmaxf(sc[0][i], sc[1][i]), fmaxf(sc[2][i], sc[3][i]));
      #pragma unroll
      for (int m = 1; m < 16; m <<= 1)
        mx = fmaxf(mx, __shfl_xor(mx, m, 64));
      const float mnew = fmaxf(mrow[i], mx);
      const float scl = __expf(mrow[i] - mnew);
      mrow[i] = mnew;
      float rsum = 0.f;
      #pragma unroll
      for (int t = 0; t < 4; ++t) {
        const float p = __expf(sc[t][i] - mnew);
        rsum += p;
        Pld[w][lg * 4 + i][t * 16 + ln] = f2b(p);
      }
      #pragma unroll
      for (int m = 1; m < 16; m <<= 1)
        rsum += __shfl_xor(rsum, m, 64);
      lrow[i] = lrow[i] * scl + rsum;
      #pragma unroll
      for (int u = 0; u < 4; ++u) zac[u][i] *= scl;
    }

    // ---- z += P * V  (B-frag from V^T rows -> D = P * (V^T)^T = P*V) ----
    #pragma unroll
    for (int c = 0; c < 2; ++c) {
      bf16x8 pa = *(const bf16x8*)&Pld[w][ln][c * 32 + lg * 8];
      #pragma unroll
      for (int u = 0; u < 4; ++u) {
        bf16x8 vb = *(const bf16x8*)&Vtld[u * 16 + ln][c * 32 + lg * 8];
        zac[u] = __builtin_amdgcn_mfma_f32_16x16x32_bf16(pa, vb, zac[u], 0, 0, 0);
      }
    }
    __syncthreads();  // before next tile's staging overwrites K/Vt
  }

  // ---- epilogue: z / l, store bf16 ----
  #pragma unroll
  for (int u = 0; u < 4; ++u) {
    #pragma unroll
    for (int i = 0; i < 4; ++i) {
      const float zv = zac[u][i] / lrow[i];
      const int qrow = qt * 64 + w * 16 + lg * 4 + i;
      zg[((size_t)(b * SEQ + qrow)) * DMODEL + h * DHEAD + u * 16 + ln] = f2b(zv);
    }
  }
}

// ---------------------------------------------------------------------------
// Kernel 2: out[m][n] = Z[m][k] * W[k][n] + b[n].  M=4096, N=1024, K=1024.
// 64x64 tile per WG; wave w owns cols w*16..w*16+15, all 64 rows.
// ---------------------------------------------------------------------------
__global__ __launch_bounds__(256) void proj_kernel(
    const unsigned short* __restrict__ z, const float* __restrict__ wo,
    const float* __restrict__ bo, float* __restrict__ out) {
  __shared__ unsigned short Zld[64][72];   // [m][k] bf16
  __shared__ unsigned short Wtld[64][72];  // [n][k] bf16 (transposed W)

  const int m0 = blockIdx.x * 64, n0 = blockIdx.y * 64;
  const int tid = (int)threadIdx.x;
  const int w = tid >> 6, lane = tid & 63, lg = lane >> 4, ln = lane & 15;

  f32x4 acc[4];
  #pragma unroll
  for (int rt = 0; rt < 4; ++rt) {
    acc[rt][0] = 0.f; acc[rt][1] = 0.f; acc[rt][2] = 0.f; acc[rt][3] = 0.f;
  }

  for (int k0 = 0; k0 < DMODEL; k0 += 64) {
    const int row = tid >> 2, quad = tid & 3;
    // Z tile: already bf16, 2x16B vector loads, linear LDS writes
    {
      const unsigned short* zp = z + (size_t)(m0 + row) * DMODEL + k0 + quad * 16;
      bf16x8 a0 = *(const bf16x8*)(zp);
      bf16x8 a1 = *(const bf16x8*)(zp + 8);
      *(bf16x8*)&Zld[row][quad * 16] = a0;
      *(bf16x8*)&Zld[row][quad * 16 + 8] = a1;
    }
    // W tile: fp32 coalesced read, bf16 transposed LDS write
    {
      const float* wp = wo + (size_t)(k0 + row) * DMODEL + n0 + quad * 16;
      #pragma unroll
      for (int j = 0; j < 4; ++j) {
        f32x4 wv = *(const f32x4*)(wp + j * 4);
        #pragma unroll
        for (int e = 0; e < 4; ++e)
          Wtld[quad * 16 + j * 4 + e][row] = f2b(wv[e]);
      }
    }
    __syncthreads();
    #pragma unroll
    for (int c = 0; c < 2; ++c) {
      bf16x8 bfrag = *(const bf16x8*)&Wtld[w * 16 + ln][c * 32 + lg * 8];
      #pragma unroll
      for (int rt = 0; rt < 4; ++rt) {
        bf16x8 afrag = *(const bf16x8*)&Zld[rt * 16 + ln][c * 32 + lg * 8];
        acc[rt] = __builtin_amdgcn_mfma_f32_16x16x32_bf16(afrag, bfrag, acc[rt], 0, 0, 0);
      }
    }
    __syncthreads();
  }

  #pragma unroll
  for (int rt = 0; rt < 4; ++rt) {
    #pragma unroll
    for (int i = 0; i < 4; ++i) {
      const int mr = m0 + rt * 16 + lg * 4 + i;
      const int nc = n0 + w * 16 + ln;
      out[(size_t)mr * DMODEL + nc] = acc[rt][i] + bo[nc];
    }
  }
}

// ---------------------------------------------------------------------------
// Kernel 3: residual pass-through (float4 copy)
// ---------------------------------------------------------------------------
__global__ __launch_bounds__(256) void copy_kernel(
    const float* __restrict__ in, float* __restrict__ out, int n4) {
  int i = blockIdx.x * blockDim.x + threadIdx.x;
  const int stride = gridDim.x * blockDim.x;
  for (; i < n4; i += stride)
    ((f32x4*)out)[i] = ((const f32x4*)in)[i];
}

extern "C" void kernel_launch(void* const* d_in, const int* in_sizes, int n_in,
                              void* d_out, int out_size, void* d_ws, size_t ws_size,
                              hipStream_t stream) {
  const float* q        = (const float*)d_in[0];
  const float* k        = (const float*)d_in[1];
  const float* v        = (const float*)d_in[2];
  const float* residual = (const float*)d_in[3];
  const float* wo       = (const float*)d_in[4];
  const float* bo       = (const float*)d_in[5];
  float* out = (float*)d_out;
  unsigned short* z = (unsigned short*)d_ws;  // [4096][1024] bf16 = 8 MB

  attn_kernel<<<dim3(BATCH * NHEADS * (SEQ / 64)), 256, 0, stream>>>(q, k, v, z);
  proj_kernel<<<dim3(BATCH * SEQ / 64, DMODEL / 64), 256, 0, stream>>>(z, wo, bo, out);
  copy_kernel<<<dim3(2048), 256, 0, stream>>>(
      residual, out + (size_t)BATCH * SEQ * DMODEL, BATCH * SEQ * DMODEL / 4);
}

// Round 2
// 246.389 us; speedup vs baseline: 1.1342x; 1.1342x over previous
//
#include <hip/hip_runtime.h>

#define BATCH 2
#define SEQ 2048
#define NHEADS 16
#define DHEAD 64
#define DMODEL 1024

typedef __attribute__((ext_vector_type(8))) short bf16x8;
typedef __attribute__((ext_vector_type(4))) float f32x4;

#define QSCALE 0.18033688011112042f  /* 0.125 * log2(e): fold /sqrt(64) and exp->exp2 */

__device__ __forceinline__ unsigned short f2b(float f) {
  union { float f; unsigned u; } a; a.f = f;
  return (unsigned short)((a.u + 0x7fffu + ((a.u >> 16) & 1u)) >> 16);
}

// ---------------------------------------------------------------------------
// Prep 1: Q,K fp32 [b,q,(h d)] -> bf16 [b,h,q,d]; Q scaled by QSCALE.
// 2^21 threads, each converts 4 contiguous d-elements.
// ---------------------------------------------------------------------------
__global__ __launch_bounds__(256) void prep_qk(
    const float* __restrict__ qg, const float* __restrict__ kg,
    unsigned short* __restrict__ qb, unsigned short* __restrict__ kb) {
  const int t = blockIdx.x * 256 + threadIdx.x;
  const int d4 = t & 15;
  const int h = (t >> 4) & 15;
  const int q = (t >> 8) & 2047;
  const int b = (t >> 19) & 1;
  const int tensor = (t >> 20) & 1;
  const float* src = (tensor ? kg : qg) +
      ((size_t)(b * SEQ + q) * DMODEL + h * DHEAD + d4 * 4);
  unsigned short* dst = (tensor ? kb : qb) +
      ((size_t)((b * NHEADS + h) * SEQ + q) * DHEAD + d4 * 4);
  const float s = tensor ? 1.0f : QSCALE;
  f32x4 v = *(const f32x4*)src;
  ushort4 o;
  o.x = f2b(v[0] * s); o.y = f2b(v[1] * s); o.z = f2b(v[2] * s); o.w = f2b(v[3] * s);
  *(ushort4*)dst = o;
}

// ---------------------------------------------------------------------------
// Prep 2: V fp32 [b,k,(h d)] -> bf16 transposed Vt [b,h,d,k]. LDS 64x64 tile.
// grid = (b*16+h)*32 + ktile
// ---------------------------------------------------------------------------
__global__ __launch_bounds__(256) void prep_vt(
    const float* __restrict__ vg, unsigned short* __restrict__ vt) {
  __shared__ unsigned short T[64][72];
  const int wg = blockIdx.x;
  const int kt = wg & 31;
  const int bh = wg >> 5;
  const int tid = (int)threadIdx.x;
  const int row = tid >> 2, quad = tid & 3;
  const int b = bh >> 4, h = bh & 15;
  {
    const float* vp = vg + (size_t)((b * SEQ + kt * 64 + row) * NHEADS + h) * DHEAD + quad * 16;
    #pragma unroll
    for (int j = 0; j < 4; ++j) {
      f32x4 x = *(const f32x4*)(vp + j * 4);
      ushort4 o;
      o.x = f2b(x[0]); o.y = f2b(x[1]); o.z = f2b(x[2]); o.w = f2b(x[3]);
      *(ushort4*)&T[row][quad * 16 + j * 4] = o;  // [k][d]
    }
  }
  __syncthreads();
  {
    unsigned short* op = vt + ((size_t)bh * DHEAD + row) * SEQ + kt * 64 + quad * 16;
    bf16x8 a, c;
    #pragma unroll
    for (int e = 0; e < 8; ++e) a[e] = (short)T[quad * 16 + e][row];
    #pragma unroll
    for (int e = 0; e < 8; ++e) c[e] = (short)T[quad * 16 + 8 + e][row];
    *(bf16x8*)op = a;
    *(bf16x8*)(op + 8) = c;
  }
}

// ---------------------------------------------------------------------------
// Prep 3: W_O fp32 [h,d,m] -> bf16 transposed Wt [m][k=h*64+d]. LDS 64x64 tile.
// grid = h*16 + mtile
// ---------------------------------------------------------------------------
__global__ __launch_bounds__(256) void prep_wt(
    const float* __restrict__ wo, unsigned short* __restrict__ wt) {
  __shared__ unsigned short T[64][72];
  const int wg = blockIdx.x;
  const int mt = wg & 15;
  const int h = wg >> 4;
  const int tid = (int)threadIdx.x;
  const int row = tid >> 2, quad = tid & 3;
  {
    const float* wp = wo + (size_t)(h * DHEAD + row) * DMODEL + mt * 64 + quad * 16;
    #pragma unroll
    for (int j = 0; j < 4; ++j) {
      f32x4 x = *(const f32x4*)(wp + j * 4);
      ushort4 o;
      o.x = f2b(x[0]); o.y = f2b(x[1]); o.z = f2b(x[2]); o.w = f2b(x[3]);
      *(ushort4*)&T[row][quad * 16 + j * 4] = o;  // [d][m_local]
    }
  }
  __syncthreads();
  {
    unsigned short* op = wt + (size_t)(mt * 64 + row) * DMODEL + h * DHEAD + quad * 16;
    bf16x8 a, c;
    #pragma unroll
    for (int e = 0; e < 8; ++e) a[e] = (short)T[quad * 16 + e][row];
    #pragma unroll
    for (int e = 0; e < 8; ++e) c[e] = (short)T[quad * 16 + 8 + e][row];
    *(bf16x8*)op = a;
    *(bf16x8*)(op + 8) = c;
  }
}

// ---------------------------------------------------------------------------
// Kernel 1: causal flash attention from pre-converted bf16 buffers.
// One WG = (b,h, 64-row q tile); qt XOR-remapped for CU load balance.
// ---------------------------------------------------------------------------
__global__ __launch_bounds__(256) void attn_kernel(
    const unsigned short* __restrict__ qb, const unsigned short* __restrict__ kb,
    const unsigned short* __restrict__ vt, unsigned short* __restrict__ zg) {
  __shared__ unsigned short Kld[64][72];    // [k_local][d]
  __shared__ unsigned short Vtld[64][72];   // [d][k_local]
  __shared__ unsigned short Pld[4][16][72]; // per-wave [q_local][k_local]

  const int wg = blockIdx.x;
  const int bh = wg >> 5;
  const int qt = (wg & 31) ^ (bh & 31);  // bijective per bh; balances CUs
  const int b = bh >> 4, h = bh & 15;
  const int tid = (int)threadIdx.x;
  const int w = tid >> 6;
  const int lane = tid & 63;
  const int lg = lane >> 4;
  const int ln = lane & 15;

  // Q fragments (pre-scaled bf16): A-frag row=ln, k elems c*32+lg*8..
  bf16x8 qf[2];
  {
    const unsigned short* qp =
        qb + ((size_t)bh * SEQ + qt * 64 + w * 16 + ln) * DHEAD;
    qf[0] = *(const bf16x8*)(qp + lg * 8);
    qf[1] = *(const bf16x8*)(qp + 32 + lg * 8);
  }

  float mrow[4], lrow[4];
  f32x4 zac[4];
  #pragma unroll
  for (int i = 0; i < 4; ++i) {
    mrow[i] = -1e30f; lrow[i] = 0.f;
    zac[i][0] = 0.f; zac[i][1] = 0.f; zac[i][2] = 0.f; zac[i][3] = 0.f;
  }

  const int row = tid >> 2, quad = tid & 3;
  const int nkt = qt + 1;
  for (int kt = 0; kt < nkt; ++kt) {
    const int k0 = kt * 64;
    // ---- stage K [k][d] and Vt [d][k] : pure 16B copies ----
    {
      const unsigned short* kp = kb + ((size_t)bh * SEQ + k0 + row) * DHEAD + quad * 16;
      const unsigned short* vp = vt + ((size_t)bh * DHEAD + row) * SEQ + k0 + quad * 16;
      *(bf16x8*)&Kld[row][quad * 16]      = *(const bf16x8*)kp;
      *(bf16x8*)&Kld[row][quad * 16 + 8]  = *(const bf16x8*)(kp + 8);
      *(bf16x8*)&Vtld[row][quad * 16]     = *(const bf16x8*)vp;
      *(bf16x8*)&Vtld[row][quad * 16 + 8] = *(const bf16x8*)(vp + 8);
    }
    __syncthreads();

    // ---- S = Qs * K^T (exp2 domain), four 16x16 col-tiles ----
    f32x4 sc[4];
    #pragma unroll
    for (int t = 0; t < 4; ++t) {
      f32x4 s = {0.f, 0.f, 0.f, 0.f};
      #pragma unroll
      for (int c = 0; c < 2; ++c) {
        bf16x8 kf = *(const bf16x8*)&Kld[t * 16 + ln][c * 32 + lg * 8];
        s = __builtin_amdgcn_mfma_f32_16x16x32_bf16(qf[c], kf, s, 0, 0, 0);
      }
      sc[t] = s;
    }

    if (kt == qt) {  // causal mask on diagonal tile
      #pragma unroll
      for (int t = 0; t < 4; ++t) {
        const int kloc = t * 16 + ln;
        #pragma unroll
        for (int i = 0; i < 4; ++i) {
          if (kloc > w * 16 + lg * 4 + i) sc[t][i] = -1e30f;
        }
      }
    }

    // ---- online softmax (exp2 domain) ----
    #pragma unroll
    for (int i = 0; i < 4; ++i) {
      float mx = fmaxf(fmaxf(sc[0][i], sc[1][i]), fmaxf(sc[2][i], sc[3][i]));
      #pragma unroll
      for (int m = 1; m < 16; m <<= 1)
        mx = fmaxf(mx, __shfl_xor(mx, m, 64));
      const float mnew = fmaxf(mrow[i], mx);
      const float scl = exp2f(mrow[i] - mnew);
      mrow[i] = mnew;
      float rsum = 0.f;
      #pragma unroll
      for (int t = 0; t < 4; ++t) {
        const float p = exp2f(sc[t][i] - mnew);
        rsum += p;
        Pld[w][lg * 4 + i][t * 16 + ln] = f2b(p);
      }
      #pragma unroll
      for (int m = 1; m < 16; m <<= 1)
        rsum += __shfl_xor(rsum, m, 64);
      lrow[i] = lrow[i] * scl + rsum;
      #pragma unroll
      for (int u = 0; u < 4; ++u) zac[u][i] *= scl;
    }

    // ---- z += P * V ----
    #pragma unroll
    for (int c = 0; c < 2; ++c) {
      bf16x8 pa = *(const bf16x8*)&Pld[w][ln][c * 32 + lg * 8];
      #pragma unroll
      for (int u = 0; u < 4; ++u) {
        bf16x8 vb = *(const bf16x8*)&Vtld[u * 16 + ln][c * 32 + lg * 8];
        zac[u] = __builtin_amdgcn_mfma_f32_16x16x32_bf16(pa, vb, zac[u], 0, 0, 0);
      }
    }
    __syncthreads();
  }

  // ---- epilogue: z/l -> bf16 in [b,q,(h d)] layout for the proj GEMM ----
  #pragma unroll
  for (int u = 0; u < 4; ++u) {
    #pragma unroll
    for (int i = 0; i < 4; ++i) {
      const float zv = zac[u][i] / lrow[i];
      const int qrow = qt * 64 + w * 16 + lg * 4 + i;
      zg[((size_t)(b * SEQ + qrow)) * DMODEL + h * DHEAD + u * 16 + ln] = f2b(zv);
    }
  }
}

// ---------------------------------------------------------------------------
// Kernel 2: out = Z * W + b.  M=4096,N=1024,K=1024. 128x128 tile, BK=64.
// 4 waves, each owns a 64x64 quadrant (4x4 16x16 frags).
// ---------------------------------------------------------------------------
__global__ __launch_bounds__(256) void proj_kernel(
    const unsigned short* __restrict__ zb, const unsigned short* __restrict__ wt,
    const float* __restrict__ bo, float* __restrict__ out) {
  __shared__ unsigned short Ald[128][72];  // [m_local][k_local]
  __shared__ unsigned short Bld[128][72];  // [n_local][k_local]

  const int m0 = blockIdx.x * 128, n0 = blockIdx.y * 128;
  const int tid = (int)threadIdx.x;
  const int w = tid >> 6, lane = tid & 63, lg = lane >> 4, ln = lane & 15;
  const int wr = w >> 1, wc = w & 1;
  const int srow = tid >> 1, shalf = tid & 1;

  f32x4 acc[4][4];
  #pragma unroll
  for (int a = 0; a < 4; ++a)
    #pragma unroll
    for (int bj = 0; bj < 4; ++bj) {
      acc[a][bj][0] = 0.f; acc[a][bj][1] = 0.f;
      acc[a][bj][2] = 0.f; acc[a][bj][3] = 0.f;
    }

  for (int k0 = 0; k0 < DMODEL; k0 += 64) {
    {
      const unsigned short* ap = zb + (size_t)(m0 + srow) * DMODEL + k0 + shalf * 32;
      const unsigned short* bp = wt + (size_t)(n0 + srow) * DMODEL + k0 + shalf * 32;
      #pragma unroll
      for (int j = 0; j < 4; ++j) {
        *(bf16x8*)&Ald[srow][shalf * 32 + j * 8] = *(const bf16x8*)(ap + j * 8);
        *(bf16x8*)&Bld[srow][shalf * 32 + j * 8] = *(const bf16x8*)(bp + j * 8);
      }
    }
    __syncthreads();
    #pragma unroll
    for (int c = 0; c < 2; ++c) {
      bf16x8 bf[4];
      #pragma unroll
      for (int bj = 0; bj < 4; ++bj)
        bf[bj] = *(const bf16x8*)&Bld[wc * 64 + bj * 16 + ln][c * 32 + lg * 8];
      #pragma unroll
      for (int a = 0; a < 4; ++a) {
        bf16x8 af = *(const bf16x8*)&Ald[wr * 64 + a * 16 + ln][c * 32 + lg * 8];
        #pragma unroll
        for (int bj = 0; bj < 4; ++bj)
          acc[a][bj] = __builtin_amdgcn_mfma_f32_16x16x32_bf16(af, bf[bj], acc[a][bj], 0, 0, 0);
      }
    }
    __syncthreads();
  }

  #pragma unroll
  for (int a = 0; a < 4; ++a)
    #pragma unroll
    for (int bj = 0; bj < 4; ++bj) {
      const int nc = n0 + wc * 64 + bj * 16 + ln;
      const float bias = bo[nc];
      #pragma unroll
      for (int i = 0; i < 4; ++i) {
        const int mr = m0 + wr * 64 + a * 16 + lg * 4 + i;
        out[(size_t)mr * DMODEL + nc] = acc[a][bj][i] + bias;
      }
    }
}

// ---------------------------------------------------------------------------
// Kernel 3: residual pass-through (float4 copy)
// ---------------------------------------------------------------------------
__global__ __launch_bounds__(256) void copy_kernel(
    const float* __restrict__ in, float* __restrict__ out, int n4) {
  int i = blockIdx.x * blockDim.x + threadIdx.x;
  const int stride = gridDim.x * blockDim.x;
  for (; i < n4; i += stride)
    ((f32x4*)out)[i] = ((const f32x4*)in)[i];
}

extern "C" void kernel_launch(void* const* d_in, const int* in_sizes, int n_in,
                              void* d_out, int out_size, void* d_ws, size_t ws_size,
                              hipStream_t stream) {
  const float* q        = (const float*)d_in[0];
  const float* k        = (const float*)d_in[1];
  const float* v        = (const float*)d_in[2];
  const float* residual = (const float*)d_in[3];
  const float* wo       = (const float*)d_in[4];
  const float* bo       = (const float*)d_in[5];
  float* out = (float*)d_out;

  const size_t QN = (size_t)BATCH * NHEADS * SEQ * DHEAD;  // 4194304
  unsigned short* qbuf = (unsigned short*)d_ws;
  unsigned short* kbuf = qbuf + QN;
  unsigned short* vtb  = qbuf + 2 * QN;
  unsigned short* wtb  = qbuf + 3 * QN;                    // 1M elems
  unsigned short* zb   = qbuf + 3 * QN + (size_t)DMODEL * DMODEL;

  prep_qk<<<dim3(8192), 256, 0, stream>>>(q, k, qbuf, kbuf);
  prep_vt<<<dim3(BATCH * NHEADS * (SEQ / 64)), 256, 0, stream>>>(v, vtb);
  prep_wt<<<dim3(NHEADS * (DMODEL / 64)), 256, 0, stream>>>(wo, wtb);
  attn_kernel<<<dim3(BATCH * NHEADS * (SEQ / 64)), 256, 0, stream>>>(qbuf, kbuf, vtb, zb);
  proj_kernel<<<dim3(BATCH * SEQ / 128, DMODEL / 128), 256, 0, stream>>>(zb, wtb, bo, out);
  copy_kernel<<<dim3(2048), 256, 0, stream>>>(
      residual, out + (size_t)BATCH * SEQ * DMODEL, BATCH * SEQ * DMODEL / 4);
}

// Round 4
// 202.060 us; speedup vs baseline: 1.3830x; 1.2194x over previous
//
#include <hip/hip_runtime.h>

#define BATCH 2
#define SEQ 2048
#define NHEADS 16
#define DHEAD 64
#define DMODEL 1024

typedef __attribute__((ext_vector_type(8))) short bf16x8;
typedef __attribute__((ext_vector_type(4))) float f32x4;

#define QSCALE 0.18033688011112042f  /* 0.125 * log2(e) */

__device__ __forceinline__ unsigned short f2b(float f) {
  union { float f; unsigned u; } a; a.f = f;
  return (unsigned short)((a.u + 0x7fffu + ((a.u >> 16) & 1u)) >> 16);
}

// pack 2 f32 -> 2 bf16 (RNE) in one instruction
__device__ __forceinline__ unsigned cvt2(float lo, float hi) {
  unsigned r;
  asm("v_cvt_pk_bf16_f32 %0, %1, %2" : "=v"(r) : "v"(lo), "v"(hi));
  return r;
}

#if defined(__has_builtin)
#if __has_builtin(__builtin_amdgcn_exp2f)
#define EXP2(x) __builtin_amdgcn_exp2f(x)
#else
#define EXP2(x) exp2f(x)
#endif
#else
#define EXP2(x) exp2f(x)
#endif

// ---------------------------------------------------------------------------
// Fused prep: [0,4096) q/k convert+relayout; [4096,5120) residual copy
// (1024 blocks x 256 thr x 16 floats = exactly 4.19M floats);
// [5120,6144) V transpose; [6144,6400) W_O transpose.
// ---------------------------------------------------------------------------
__global__ __launch_bounds__(256) void prep_kernel(
    const float* __restrict__ qg, const float* __restrict__ kg,
    const float* __restrict__ vg, const float* __restrict__ wo,
    const float* __restrict__ residual,
    unsigned short* __restrict__ qb, unsigned short* __restrict__ kb,
    unsigned short* __restrict__ vt, unsigned short* __restrict__ wt,
    float* __restrict__ res_out) {
  __shared__ unsigned short T[64][72];
  const int blk = blockIdx.x;
  const int tid = (int)threadIdx.x;

  if (blk < 4096) {  // q,k: fp32 [b,s,(h d)] -> bf16 [b,h,s,d] (q scaled)
    const int t = blk * 256 + tid;
    const int d8 = t & 7;
    const int h = (t >> 3) & 15;
    const int q = (t >> 7) & 2047;
    const int b = (t >> 18) & 1;
    const int tensor = (t >> 19) & 1;
    const float* src = (tensor ? kg : qg) +
        ((size_t)(b * SEQ + q) * DMODEL + h * DHEAD + d8 * 8);
    unsigned short* dst = (tensor ? kb : qb) +
        ((size_t)((b * NHEADS + h) * SEQ + q) * DHEAD + d8 * 8);
    const float s = tensor ? 1.0f : QSCALE;
    f32x4 v0 = *(const f32x4*)src;
    f32x4 v1 = *(const f32x4*)(src + 4);
    ushort4 o0, o1;
    o0.x = f2b(v0[0] * s); o0.y = f2b(v0[1] * s);
    o0.z = f2b(v0[2] * s); o0.w = f2b(v0[3] * s);
    o1.x = f2b(v1[0] * s); o1.y = f2b(v1[1] * s);
    o1.z = f2b(v1[2] * s); o1.w = f2b(v1[3] * s);
    *(ushort4*)dst = o0;
    *(ushort4*)(dst + 4) = o1;
  } else if (blk < 5120) {  // residual copy: 16 floats/thread, 1024 blocks
    const size_t i = ((size_t)(blk - 4096) * 256 + tid) * 16;
    #pragma unroll
    for (int j = 0; j < 4; ++j)
      *(f32x4*)(res_out + i + j * 4) = *(const f32x4*)(residual + i + j * 4);
  } else if (blk < 6144) {  // V -> Vt [b,h,d,k]
    const int wg = blk - 5120;
    const int kt = wg & 31;
    const int bh = wg >> 5;
    const int row = tid >> 2, quad = tid & 3;
    const int b = bh >> 4, h = bh & 15;
    const float* vp = vg + (size_t)(b * SEQ + kt * 64 + row) * DMODEL + h * DHEAD + quad * 16;
    #pragma unroll
    for (int j = 0; j < 4; ++j) {
      f32x4 x = *(const f32x4*)(vp + j * 4);
      ushort4 o;
      o.x = f2b(x[0]); o.y = f2b(x[1]); o.z = f2b(x[2]); o.w = f2b(x[3]);
      *(ushort4*)&T[row][quad * 16 + j * 4] = o;
    }
    __syncthreads();
    unsigned short* op = vt + ((size_t)bh * DHEAD + row) * SEQ + kt * 64 + quad * 16;
    bf16x8 a, c;
    #pragma unroll
    for (int e = 0; e < 8; ++e) a[e] = (short)T[quad * 16 + e][row];
    #pragma unroll
    for (int e = 0; e < 8; ++e) c[e] = (short)T[quad * 16 + 8 + e][row];
    *(bf16x8*)op = a;
    *(bf16x8*)(op + 8) = c;
  } else {  // W_O [h,d,m] -> Wt [m][h*64+d]
    const int wg = blk - 6144;
    const int mt = wg & 15;
    const int h = wg >> 4;
    const int row = tid >> 2, quad = tid & 3;
    const float* wp = wo + (size_t)(h * DHEAD + row) * DMODEL + mt * 64 + quad * 16;
    #pragma unroll
    for (int j = 0; j < 4; ++j) {
      f32x4 x = *(const f32x4*)(wp + j * 4);
      ushort4 o;
      o.x = f2b(x[0]); o.y = f2b(x[1]); o.z = f2b(x[2]); o.w = f2b(x[3]);
      *(ushort4*)&T[row][quad * 16 + j * 4] = o;
    }
    __syncthreads();
    unsigned short* op = wt + (size_t)(mt * 64 + row) * DMODEL + h * DHEAD + quad * 16;
    bf16x8 a, c;
    #pragma unroll
    for (int e = 0; e < 8; ++e) a[e] = (short)T[quad * 16 + e][row];
    #pragma unroll
    for (int e = 0; e < 8; ++e) c[e] = (short)T[quad * 16 + 8 + e][row];
    *(bf16x8*)op = a;
    *(bf16x8*)(op + 8) = c;
  }
}

// ---------------------------------------------------------------------------
// Kernel 1: causal flash attention, swapped QK^T (S^T = K*Q^T) so each lane
// owns one q-row: row-reduce = in-reg + 2 shuffles; P-store = packed 8B.
// XCD-chunked block swizzle + qt-XOR CU balance.
// ---------------------------------------------------------------------------
__global__ __launch_bounds__(256) void attn_kernel(
    const unsigned short* __restrict__ qb, const unsigned short* __restrict__ kb,
    const unsigned short* __restrict__ vt, unsigned short* __restrict__ zg) {
  __shared__ unsigned short Kld[64][72];    // [k_local][d]
  __shared__ unsigned short Vtld[64][72];   // [d][k_local]
  __shared__ unsigned short Pld[4][16][72]; // per-wave [q_local(16)][k_local]

  // XCD-chunked: dispatch d -> XCD d%8; give each XCD 128 contiguous wgs (4 bh)
  const int wg = (blockIdx.x & 7) * 128 + (blockIdx.x >> 3);
  const int bh = wg >> 5;
  const int qt = (wg & 31) ^ (bh & 31);  // per-CU work balance
  const int tid = (int)threadIdx.x;
  const int w = tid >> 6;
  const int lane = tid & 63;
  const int lg = lane >> 4;
  const int ln = lane & 15;

  // Q fragment (pre-scaled): supplies q-row w*16+ln, d elems c*32+lg*8..
  bf16x8 qf[2];
  {
    const unsigned short* qp =
        qb + ((size_t)bh * SEQ + qt * 64 + w * 16 + ln) * DHEAD;
    qf[0] = *(const bf16x8*)(qp + lg * 8);
    qf[1] = *(const bf16x8*)(qp + 32 + lg * 8);
  }

  float mrow = -1e30f, lrow = 0.f;
  f32x4 zac[4];  // zac[u][reg] = z[q=lg*4+reg][d=u*16+ln]
  #pragma unroll
  for (int u = 0; u < 4; ++u) {
    zac[u][0] = 0.f; zac[u][1] = 0.f; zac[u][2] = 0.f; zac[u][3] = 0.f;
  }

  const int row = tid >> 2, quad = tid & 3;
  const int nkt = qt + 1;
  for (int kt = 0; kt < nkt; ++kt) {
    const int k0 = kt * 64;
    {  // stage K [k][d], Vt [d][k]: pure 16B copies
      const unsigned short* kp = kb + ((size_t)bh * SEQ + k0 + row) * DHEAD + quad * 16;
      const unsigned short* vp = vt + ((size_t)bh * DHEAD + row) * SEQ + k0 + quad * 16;
      *(bf16x8*)&Kld[row][quad * 16]      = *(const bf16x8*)kp;
      *(bf16x8*)&Kld[row][quad * 16 + 8]  = *(const bf16x8*)(kp + 8);
      *(bf16x8*)&Vtld[row][quad * 16]     = *(const bf16x8*)vp;
      *(bf16x8*)&Vtld[row][quad * 16 + 8] = *(const bf16x8*)(vp + 8);
    }
    __syncthreads();

    // ---- S^T = K * Q^T: lane holds S[k=t*16+lg*4+reg][q=w*16+ln] ----
    f32x4 sc[4];
    #pragma unroll
    for (int t = 0; t < 4; ++t) {
      f32x4 s = {0.f, 0.f, 0.f, 0.f};
      #pragma unroll
      for (int c = 0; c < 2; ++c) {
        bf16x8 kf = *(const bf16x8*)&Kld[t * 16 + ln][c * 32 + lg * 8];
        s = __builtin_amdgcn_mfma_f32_16x16x32_bf16(kf, qf[c], s, 0, 0, 0);
      }
      sc[t] = s;
    }

    if (kt == qt) {  // causal mask: k_local > q_local
      const int qloc = w * 16 + ln;
      #pragma unroll
      for (int t = 0; t < 4; ++t) {
        #pragma unroll
        for (int r = 0; r < 4; ++r) {
          if (t * 16 + lg * 4 + r > qloc) sc[t][r] = -1e30f;
        }
      }
    }

    // ---- online softmax: per-lane single row ----
    float mx = sc[0][0];
    #pragma unroll
    for (int t = 0; t < 4; ++t) {
      #pragma unroll
      for (int r = 0; r < 4; ++r) mx = fmaxf(mx, sc[t][r]);
    }
    mx = fmaxf(mx, __shfl_xor(mx, 16, 64));
    mx = fmaxf(mx, __shfl_xor(mx, 32, 64));

    if (!__all(mx <= mrow + 8.f)) {  // rescale needed (wave-uniform)
      const float mnew = fmaxf(mrow, mx);
      const float scl = EXP2(mrow - mnew);
      mrow = mnew;
      lrow *= scl;
      const int sbase = lane & 48;
      const float s0 = __shfl(scl, sbase | (lg * 4 + 0), 64);
      const float s1 = __shfl(scl, sbase | (lg * 4 + 1), 64);
      const float s2 = __shfl(scl, sbase | (lg * 4 + 2), 64);
      const float s3 = __shfl(scl, sbase | (lg * 4 + 3), 64);
      #pragma unroll
      for (int u = 0; u < 4; ++u) {
        zac[u][0] *= s0; zac[u][1] *= s1; zac[u][2] *= s2; zac[u][3] *= s3;
      }
    }

    float rsum = 0.f;
    #pragma unroll
    for (int t = 0; t < 4; ++t) {
      const float p0 = EXP2(sc[t][0] - mrow);
      const float p1 = EXP2(sc[t][1] - mrow);
      const float p2 = EXP2(sc[t][2] - mrow);
      const float p3 = EXP2(sc[t][3] - mrow);
      rsum += (p0 + p1) + (p2 + p3);
      uint2 pk;
      pk.x = cvt2(p0, p1);
      pk.y = cvt2(p2, p3);
      *(uint2*)&Pld[w][ln][t * 16 + lg * 4] = pk;  // P[q=ln][k=t*16+lg*4..+3]
    }
    rsum += __shfl_xor(rsum, 16, 64);
    rsum += __shfl_xor(rsum, 32, 64);
    lrow += rsum;

    // ---- z += P * V ----
    #pragma unroll
    for (int c = 0; c < 2; ++c) {
      bf16x8 pa = *(const bf16x8*)&Pld[w][ln][c * 32 + lg * 8];
      #pragma unroll
      for (int u = 0; u < 4; ++u) {
        bf16x8 vb = *(const bf16x8*)&Vtld[u * 16 + ln][c * 32 + lg * 8];
        zac[u] = __builtin_amdgcn_mfma_f32_16x16x32_bf16(pa, vb, zac[u], 0, 0, 0);
      }
    }
    __syncthreads();
  }

  // ---- epilogue: z/l -> bf16 [b,q,(h d)] ----
  const int b = bh >> 4, h = bh & 15;
  const int sbase = lane & 48;
  float rl[4];
  #pragma unroll
  for (int i = 0; i < 4; ++i)
    rl[i] = 1.0f / __shfl(lrow, sbase | (lg * 4 + i), 64);
  #pragma unroll
  for (int u = 0; u < 4; ++u) {
    #pragma unroll
    for (int i = 0; i < 4; ++i) {
      const int qrow = qt * 64 + w * 16 + lg * 4 + i;
      zg[((size_t)(b * SEQ + qrow)) * DMODEL + h * DHEAD + u * 16 + ln] =
          f2b(zac[u][i] * rl[i]);
    }
  }
}

// ---------------------------------------------------------------------------
// Kernel 2: out = Z * Wt^T + b. 128x64 tile (512 WGs = 2/CU), BK=64,
// register-prefetch pipeline (T14): issue next tile's loads before MFMA.
// ---------------------------------------------------------------------------
__global__ __launch_bounds__(256) void proj_kernel(
    const unsigned short* __restrict__ zb, const unsigned short* __restrict__ wt,
    const float* __restrict__ bo, float* __restrict__ out) {
  __shared__ unsigned short Ald[128][72];  // [m_local][k]
  __shared__ unsigned short Bld[64][72];   // [n_local][k]

  const int m0 = blockIdx.x * 128, n0 = blockIdx.y * 64;
  const int tid = (int)threadIdx.x;
  const int w = tid >> 6, lane = tid & 63, lg = lane >> 4, ln = lane & 15;
  const int wr = w >> 1, wc = w & 1;  // wave quadrant: 64 rows x 32 cols

  const int arow = tid >> 1, acol = (tid & 1) * 32;   // A: 4x16B per thread
  const int brow = tid >> 2, bcol = (tid & 3) * 16;   // B: 2x16B per thread

  f32x4 acc[4][2];
  #pragma unroll
  for (int a = 0; a < 4; ++a)
    #pragma unroll
    for (int bj = 0; bj < 2; ++bj) {
      acc[a][bj][0] = 0.f; acc[a][bj][1] = 0.f;
      acc[a][bj][2] = 0.f; acc[a][bj][3] = 0.f;
    }

  bf16x8 ra[4], rb[2];
  {
    const unsigned short* ap = zb + (size_t)(m0 + arow) * DMODEL + acol;
    const unsigned short* bp = wt + (size_t)(n0 + brow) * DMODEL + bcol;
    #pragma unroll
    for (int j = 0; j < 4; ++j) ra[j] = *(const bf16x8*)(ap + j * 8);
    rb[0] = *(const bf16x8*)(bp);
    rb[1] = *(const bf16x8*)(bp + 8);
  }

  for (int ks = 0; ks < DMODEL / 64; ++ks) {
    __syncthreads();  // prev MFMA done reading LDS
    #pragma unroll
    for (int j = 0; j < 4; ++j) *(bf16x8*)&Ald[arow][acol + j * 8] = ra[j];
    *(bf16x8*)&Bld[brow][bcol]     = rb[0];
    *(bf16x8*)&Bld[brow][bcol + 8] = rb[1];
    __syncthreads();

    if (ks + 1 < DMODEL / 64) {  // prefetch next tile into regs (hides latency)
      const int k0 = (ks + 1) * 64;
      const unsigned short* ap = zb + (size_t)(m0 + arow) * DMODEL + k0 + acol;
      const unsigned short* bp = wt + (size_t)(n0 + brow) * DMODEL + k0 + bcol;
      #pragma unroll
      for (int j = 0; j < 4; ++j) ra[j] = *(const bf16x8*)(ap + j * 8);
      rb[0] = *(const bf16x8*)(bp);
      rb[1] = *(const bf16x8*)(bp + 8);
    }

    #pragma unroll
    for (int c = 0; c < 2; ++c) {
      bf16x8 bf[2];
      #pragma unroll
      for (int bj = 0; bj < 2; ++bj)
        bf[bj] = *(const bf16x8*)&Bld[wc * 32 + bj * 16 + ln][c * 32 + lg * 8];
      #pragma unroll
      for (int a = 0; a < 4; ++a) {
        bf16x8 af = *(const bf16x8*)&Ald[wr * 64 + a * 16 + ln][c * 32 + lg * 8];
        #pragma unroll
        for (int bj = 0; bj < 2; ++bj)
          acc[a][bj] = __builtin_amdgcn_mfma_f32_16x16x32_bf16(af, bf[bj], acc[a][bj], 0, 0, 0);
      }
    }
  }

  #pragma unroll
  for (int a = 0; a < 4; ++a)
    #pragma unroll
    for (int bj = 0; bj < 2; ++bj) {
      const int nc = n0 + wc * 32 + bj * 16 + ln;
      const float bias = bo[nc];
      #pragma unroll
      for (int i = 0; i < 4; ++i) {
        const int mr = m0 + wr * 64 + a * 16 + lg * 4 + i;
        out[(size_t)mr * DMODEL + nc] = acc[a][bj][i] + bias;
      }
    }
}

extern "C" void kernel_launch(void* const* d_in, const int* in_sizes, int n_in,
                              void* d_out, int out_size, void* d_ws, size_t ws_size,
                              hipStream_t stream) {
  const float* q        = (const float*)d_in[0];
  const float* k        = (const float*)d_in[1];
  const float* v        = (const float*)d_in[2];
  const float* residual = (const float*)d_in[3];
  const float* wo       = (const float*)d_in[4];
  const float* bo       = (const float*)d_in[5];
  float* out = (float*)d_out;

  const size_t QN = (size_t)BATCH * NHEADS * SEQ * DHEAD;  // 4 Mi elems
  unsigned short* qbuf = (unsigned short*)d_ws;
  unsigned short* kbuf = qbuf + QN;
  unsigned short* vtb  = qbuf + 2 * QN;
  unsigned short* wtb  = qbuf + 3 * QN;
  unsigned short* zb   = qbuf + 3 * QN + (size_t)DMODEL * DMODEL;

  prep_kernel<<<dim3(6400), 256, 0, stream>>>(
      q, k, v, wo, residual, qbuf, kbuf, vtb, wtb,
      out + (size_t)BATCH * SEQ * DMODEL);
  attn_kernel<<<dim3(BATCH * NHEADS * (SEQ / 64)), 256, 0, stream>>>(qbuf, kbuf, vtb, zb);
  proj_kernel<<<dim3(BATCH * SEQ / 128, DMODEL / 64), 256, 0, stream>>>(zb, wtb, bo, out);
}

// Round 8
// 196.243 us; speedup vs baseline: 1.4240x; 1.0296x over previous
//
#include <hip/hip_runtime.h>

#define BATCH 2
#define SEQ 2048
#define NHEADS 16
#define DHEAD 64
#define DMODEL 1024

typedef __attribute__((ext_vector_type(8))) short bf16x8;
typedef __attribute__((ext_vector_type(4))) float f32x4;

#define QSCALE 0.18033688011112042f  /* 0.125 * log2(e) */

__device__ __forceinline__ unsigned short f2b(float f) {
  union { float f; unsigned u; } a; a.f = f;
  return (unsigned short)((a.u + 0x7fffu + ((a.u >> 16) & 1u)) >> 16);
}

__device__ __forceinline__ unsigned cvt2(float lo, float hi) {
  unsigned r;
  asm("v_cvt_pk_bf16_f32 %0, %1, %2" : "=v"(r) : "v"(lo), "v"(hi));
  return r;
}

#define EXP2(x) exp2f(x)

// ---------------------------------------------------------------------------
// Fused prep: [0,4096) q/k convert+relayout; [4096,5120) residual copy;
// [5120,6144) V transpose; [6144,6400) W_O transpose.
// ---------------------------------------------------------------------------
__global__ __launch_bounds__(256) void prep_kernel(
    const float* __restrict__ qg, const float* __restrict__ kg,
    const float* __restrict__ vg, const float* __restrict__ wo,
    const float* __restrict__ residual,
    unsigned short* __restrict__ qb, unsigned short* __restrict__ kb,
    unsigned short* __restrict__ vt, unsigned short* __restrict__ wt,
    float* __restrict__ res_out) {
  __shared__ unsigned short T[64][72];
  const int blk = blockIdx.x;
  const int tid = (int)threadIdx.x;

  if (blk < 4096) {  // q,k: fp32 [b,s,(h d)] -> bf16 [b,h,s,d] (q scaled)
    const int t = blk * 256 + tid;
    const int d8 = t & 7;
    const int h = (t >> 3) & 15;
    const int q = (t >> 7) & 2047;
    const int b = (t >> 18) & 1;
    const int tensor = (t >> 19) & 1;
    const float* src = (tensor ? kg : qg) +
        ((size_t)(b * SEQ + q) * DMODEL + h * DHEAD + d8 * 8);
    unsigned short* dst = (tensor ? kb : qb) +
        ((size_t)((b * NHEADS + h) * SEQ + q) * DHEAD + d8 * 8);
    const float s = tensor ? 1.0f : QSCALE;
    f32x4 v0 = *(const f32x4*)src;
    f32x4 v1 = *(const f32x4*)(src + 4);
    ushort4 o0, o1;
    o0.x = f2b(v0[0] * s); o0.y = f2b(v0[1] * s);
    o0.z = f2b(v0[2] * s); o0.w = f2b(v0[3] * s);
    o1.x = f2b(v1[0] * s); o1.y = f2b(v1[1] * s);
    o1.z = f2b(v1[2] * s); o1.w = f2b(v1[3] * s);
    *(ushort4*)dst = o0;
    *(ushort4*)(dst + 4) = o1;
  } else if (blk < 5120) {  // residual copy: 16 floats/thread, 1024 blocks
    const size_t i = ((size_t)(blk - 4096) * 256 + tid) * 16;
    #pragma unroll
    for (int j = 0; j < 4; ++j)
      *(f32x4*)(res_out + i + j * 4) = *(const f32x4*)(residual + i + j * 4);
  } else if (blk < 6144) {  // V -> Vt [b,h,d,k]
    const int wg = blk - 5120;
    const int kt = wg & 31;
    const int bh = wg >> 5;
    const int row = tid >> 2, quad = tid & 3;
    const int b = bh >> 4, h = bh & 15;
    const float* vp = vg + (size_t)(b * SEQ + kt * 64 + row) * DMODEL + h * DHEAD + quad * 16;
    #pragma unroll
    for (int j = 0; j < 4; ++j) {
      f32x4 x = *(const f32x4*)(vp + j * 4);
      ushort4 o;
      o.x = f2b(x[0]); o.y = f2b(x[1]); o.z = f2b(x[2]); o.w = f2b(x[3]);
      *(ushort4*)&T[row][quad * 16 + j * 4] = o;
    }
    __syncthreads();
    unsigned short* op = vt + ((size_t)bh * DHEAD + row) * SEQ + kt * 64 + quad * 16;
    bf16x8 a, c;
    #pragma unroll
    for (int e = 0; e < 8; ++e) a[e] = (short)T[quad * 16 + e][row];
    #pragma unroll
    for (int e = 0; e < 8; ++e) c[e] = (short)T[quad * 16 + 8 + e][row];
    *(bf16x8*)op = a;
    *(bf16x8*)(op + 8) = c;
  } else {  // W_O [h,d,m] -> Wt [m][h*64+d]
    const int wg = blk - 6144;
    const int mt = wg & 15;
    const int h = wg >> 4;
    const int row = tid >> 2, quad = tid & 3;
    const float* wp = wo + (size_t)(h * DHEAD + row) * DMODEL + mt * 64 + quad * 16;
    #pragma unroll
    for (int j = 0; j < 4; ++j) {
      f32x4 x = *(const f32x4*)(wp + j * 4);
      ushort4 o;
      o.x = f2b(x[0]); o.y = f2b(x[1]); o.z = f2b(x[2]); o.w = f2b(x[3]);
      *(ushort4*)&T[row][quad * 16 + j * 4] = o;
    }
    __syncthreads();
    unsigned short* op = wt + (size_t)(mt * 64 + row) * DMODEL + h * DHEAD + quad * 16;
    bf16x8 a, c;
    #pragma unroll
    for (int e = 0; e < 8; ++e) a[e] = (short)T[quad * 16 + e][row];
    #pragma unroll
    for (int e = 0; e < 8; ++e) c[e] = (short)T[quad * 16 + 8 + e][row];
    *(bf16x8*)op = a;
    *(bf16x8*)(op + 8) = c;
  }
}

// ---------------------------------------------------------------------------
// Kernel 1: causal flash attention; swapped QK^T (lane owns one q-row).
// Each WG handles TWO q-tiles of the same (b,h): qtA=i, qtB=31-i, sharing one
// k-loop and one staging pass => uniform 33 tile-computes per WG.
// Reg-prefetch of next K/V tile hides global latency. Grid 512, XCD-chunked.
// ---------------------------------------------------------------------------
__global__ __launch_bounds__(256) void attn_kernel(
    const unsigned short* __restrict__ qb, const unsigned short* __restrict__ kb,
    const unsigned short* __restrict__ vt, unsigned short* __restrict__ zg) {
  __shared__ unsigned short Kld[64][68];    // [k_local][d]   (pad 68: 2-dw bank stride)
  __shared__ unsigned short Vtld[64][68];   // [d][k_local]
  __shared__ unsigned short Pld[4][16][68]; // per-wave [q_local(16)][k_local]

  // XCD-chunked: 64 consecutive wg (4 bh) per XCD
  const int wg = (blockIdx.x & 7) * 64 + (blockIdx.x >> 3);
  const int bh = wg >> 4;
  const int ip = wg & 15;
  const int qtA = ip, qtB = 31 - ip;
  const int tid = (int)threadIdx.x;
  const int w = tid >> 6;
  const int lane = tid & 63;
  const int lg = lane >> 4;
  const int ln = lane & 15;

  bf16x8 qfA[2], qfB[2];
  {
    const unsigned short* qpA =
        qb + ((size_t)bh * SEQ + qtA * 64 + w * 16 + ln) * DHEAD;
    const unsigned short* qpB =
        qb + ((size_t)bh * SEQ + qtB * 64 + w * 16 + ln) * DHEAD;
    qfA[0] = *(const bf16x8*)(qpA + lg * 8);
    qfA[1] = *(const bf16x8*)(qpA + 32 + lg * 8);
    qfB[0] = *(const bf16x8*)(qpB + lg * 8);
    qfB[1] = *(const bf16x8*)(qpB + 32 + lg * 8);
  }

  float mA = -1e30f, lA = 0.f, mB = -1e30f, lB = 0.f;
  f32x4 zacA[4], zacB[4];
  #pragma unroll
  for (int u = 0; u < 4; ++u) {
    zacA[u][0] = 0.f; zacA[u][1] = 0.f; zacA[u][2] = 0.f; zacA[u][3] = 0.f;
    zacB[u][0] = 0.f; zacB[u][1] = 0.f; zacB[u][2] = 0.f; zacB[u][3] = 0.f;
  }

  const int row = tid >> 2, quad = tid & 3;
  const unsigned short* kbase = kb + (size_t)bh * SEQ * DHEAD;
  const unsigned short* vbase = vt + (size_t)bh * DHEAD * SEQ;

  // one tile-compute for state (qf, m, l, zac)
  auto compute = [&](const bf16x8* qf, float& mrow, float& lrow, f32x4* zac,
                     bool diag) {
    f32x4 sc[4];
    #pragma unroll
    for (int t = 0; t < 4; ++t) {
      f32x4 s = {0.f, 0.f, 0.f, 0.f};
      #pragma unroll
      for (int c = 0; c < 2; ++c) {
        bf16x8 kf = *(const bf16x8*)&Kld[t * 16 + ln][c * 32 + lg * 8];
        s = __builtin_amdgcn_mfma_f32_16x16x32_bf16(kf, qf[c], s, 0, 0, 0);
      }
      sc[t] = s;
    }
    if (diag) {  // causal mask: k_local > q_local
      const int qloc = w * 16 + ln;
      #pragma unroll
      for (int t = 0; t < 4; ++t)
        #pragma unroll
        for (int r = 0; r < 4; ++r)
          if (t * 16 + lg * 4 + r > qloc) sc[t][r] = -1e30f;
    }
    float mx = sc[0][0];
    #pragma unroll
    for (int t = 0; t < 4; ++t)
      #pragma unroll
      for (int r = 0; r < 4; ++r) mx = fmaxf(mx, sc[t][r]);
    mx = fmaxf(mx, __shfl_xor(mx, 16, 64));
    mx = fmaxf(mx, __shfl_xor(mx, 32, 64));

    if (!__all(mx <= mrow + 8.f)) {  // defer-max rescale (wave-uniform)
      const float mnew = fmaxf(mrow, mx);
      const float scl = EXP2(mrow - mnew);
      mrow = mnew;
      lrow *= scl;
      const int sbase = lane & 48;
      const float s0 = __shfl(scl, sbase | (lg * 4 + 0), 64);
      const float s1 = __shfl(scl, sbase | (lg * 4 + 1), 64);
      const float s2 = __shfl(scl, sbase | (lg * 4 + 2), 64);
      const float s3 = __shfl(scl, sbase | (lg * 4 + 3), 64);
      #pragma unroll
      for (int u = 0; u < 4; ++u) {
        zac[u][0] *= s0; zac[u][1] *= s1; zac[u][2] *= s2; zac[u][3] *= s3;
      }
    }

    float rsum = 0.f;
    #pragma unroll
    for (int t = 0; t < 4; ++t) {
      const float p0 = EXP2(sc[t][0] - mrow);
      const float p1 = EXP2(sc[t][1] - mrow);
      const float p2 = EXP2(sc[t][2] - mrow);
      const float p3 = EXP2(sc[t][3] - mrow);
      rsum += (p0 + p1) + (p2 + p3);
      uint2 pk;
      pk.x = cvt2(p0, p1);
      pk.y = cvt2(p2, p3);
      *(uint2*)&Pld[w][ln][t * 16 + lg * 4] = pk;
    }
    rsum += __shfl_xor(rsum, 16, 64);
    rsum += __shfl_xor(rsum, 32, 64);
    lrow += rsum;

    #pragma unroll
    for (int c = 0; c < 2; ++c) {
      bf16x8 pa = *(const bf16x8*)&Pld[w][ln][c * 32 + lg * 8];
      #pragma unroll
      for (int u = 0; u < 4; ++u) {
        bf16x8 vb = *(const bf16x8*)&Vtld[u * 16 + ln][c * 32 + lg * 8];
        zac[u] = __builtin_amdgcn_mfma_f32_16x16x32_bf16(pa, vb, zac[u], 0, 0, 0);
      }
    }
  };

  const int nkt = qtB + 1;  // tiles 0..31-ip
  bf16x8 rk0, rk1, rv0, rv1;
  {  // prefetch tile 0
    const unsigned short* kp = kbase + (size_t)row * DHEAD + quad * 16;
    const unsigned short* vp = vbase + (size_t)row * SEQ + quad * 16;
    rk0 = *(const bf16x8*)kp;  rk1 = *(const bf16x8*)(kp + 8);
    rv0 = *(const bf16x8*)vp;  rv1 = *(const bf16x8*)(vp + 8);
  }

  for (int kt = 0; kt < nkt; ++kt) {
    if (kt) __syncthreads();  // previous compute done reading LDS
    *(bf16x8*)&Kld[row][quad * 16]      = rk0;
    *(bf16x8*)&Kld[row][quad * 16 + 8]  = rk1;
    *(bf16x8*)&Vtld[row][quad * 16]     = rv0;
    *(bf16x8*)&Vtld[row][quad * 16 + 8] = rv1;
    __syncthreads();
    if (kt + 1 < nkt) {  // issue next tile's loads; latency hides under compute
      const int k0 = (kt + 1) * 64;
      const unsigned short* kp = kbase + (size_t)(k0 + row) * DHEAD + quad * 16;
      const unsigned short* vp = vbase + (size_t)row * SEQ + k0 + quad * 16;
      rk0 = *(const bf16x8*)kp;  rk1 = *(const bf16x8*)(kp + 8);
      rv0 = *(const bf16x8*)vp;  rv1 = *(const bf16x8*)(vp + 8);
    }
    if (kt <= qtA) compute(qfA, mA, lA, zacA, kt == qtA);
    compute(qfB, mB, lB, zacB, kt == qtB);
  }

  // ---- epilogues ----
  const int b = bh >> 4, h = bh & 15;
  const int sbase = lane & 48;
  auto epi = [&](int qt, float lrow, const f32x4* zac) {
    float rl[4];
    #pragma unroll
    for (int i = 0; i < 4; ++i)
      rl[i] = 1.0f / __shfl(lrow, sbase | (lg * 4 + i), 64);
    #pragma unroll
    for (int u = 0; u < 4; ++u)
      #pragma unroll
      for (int i = 0; i < 4; ++i) {
        const int qrow = qt * 64 + w * 16 + lg * 4 + i;
        zg[((size_t)(b * SEQ + qrow)) * DMODEL + h * DHEAD + u * 16 + ln] =
            f2b(zac[u][i] * rl[i]);
      }
  };
  epi(qtA, lA, zacA);
  epi(qtB, lB, zacB);
}

// ---------------------------------------------------------------------------
// Kernel 2: out = Z * Wt^T + b. 128x64 tile, BK=128 (8 iters), reg-prefetch.
// ---------------------------------------------------------------------------
__global__ __launch_bounds__(256) void proj_kernel(
    const unsigned short* __restrict__ zb, const unsigned short* __restrict__ wt,
    const float* __restrict__ bo, float* __restrict__ out) {
  __shared__ unsigned short Ald[128][136];  // [m_local][k], pad 136
  __shared__ unsigned short Bld[64][136];   // [n_local][k]

  const int m0 = blockIdx.x * 128, n0 = blockIdx.y * 64;
  const int tid = (int)threadIdx.x;
  const int w = tid >> 6, lane = tid & 63, lg = lane >> 4, ln = lane & 15;
  const int wr = w >> 1, wc = w & 1;  // wave quadrant: 64 rows x 32 cols

  const int arow = tid >> 1, acol = (tid & 1) * 64;   // A: 8x16B per thread
  const int brow = tid >> 2, bcol = (tid & 3) * 32;   // B: 4x16B per thread

  f32x4 acc[4][2];
  #pragma unroll
  for (int a = 0; a < 4; ++a)
    #pragma unroll
    for (int bj = 0; bj < 2; ++bj) {
      acc[a][bj][0] = 0.f; acc[a][bj][1] = 0.f;
      acc[a][bj][2] = 0.f; acc[a][bj][3] = 0.f;
    }

  bf16x8 ra[8], rb[4];
  {
    const unsigned short* ap = zb + (size_t)(m0 + arow) * DMODEL + acol;
    const unsigned short* bp = wt + (size_t)(n0 + brow) * DMODEL + bcol;
    #pragma unroll
    for (int j = 0; j < 8; ++j) ra[j] = *(const bf16x8*)(ap + j * 8);
    #pragma unroll
    for (int j = 0; j < 4; ++j) rb[j] = *(const bf16x8*)(bp + j * 8);
  }

  for (int ks = 0; ks < DMODEL / 128; ++ks) {
    if (ks) __syncthreads();
    #pragma unroll
    for (int j = 0; j < 8; ++j) *(bf16x8*)&Ald[arow][acol + j * 8] = ra[j];
    #pragma unroll
    for (int j = 0; j < 4; ++j) *(bf16x8*)&Bld[brow][bcol + j * 8] = rb[j];
    __syncthreads();

    if (ks + 1 < DMODEL / 128) {
      const int k0 = (ks + 1) * 128;
      const unsigned short* ap = zb + (size_t)(m0 + arow) * DMODEL + k0 + acol;
      const unsigned short* bp = wt + (size_t)(n0 + brow) * DMODEL + k0 + bcol;
      #pragma unroll
      for (int j = 0; j < 8; ++j) ra[j] = *(const bf16x8*)(ap + j * 8);
      #pragma unroll
      for (int j = 0; j < 4; ++j) rb[j] = *(const bf16x8*)(bp + j * 8);
    }

    #pragma unroll
    for (int c = 0; c < 4; ++c) {
      bf16x8 bf[2];
      #pragma unroll
      for (int bj = 0; bj < 2; ++bj)
        bf[bj] = *(const bf16x8*)&Bld[wc * 32 + bj * 16 + ln][c * 32 + lg * 8];
      #pragma unroll
      for (int a = 0; a < 4; ++a) {
        bf16x8 af = *(const bf16x8*)&Ald[wr * 64 + a * 16 + ln][c * 32 + lg * 8];
        #pragma unroll
        for (int bj = 0; bj < 2; ++bj)
          acc[a][bj] = __builtin_amdgcn_mfma_f32_16x16x32_bf16(af, bf[bj], acc[a][bj], 0, 0, 0);
      }
    }
  }

  #pragma unroll
  for (int a = 0; a < 4; ++a)
    #pragma unroll
    for (int bj = 0; bj < 2; ++bj) {
      const int nc = n0 + wc * 32 + bj * 16 + ln;
      const float bias = bo[nc];
      #pragma unroll
      for (int i = 0; i < 4; ++i) {
        const int mr = m0 + wr * 64 + a * 16 + lg * 4 + i;
        out[(size_t)mr * DMODEL + nc] = acc[a][bj][i] + bias;
      }
    }
}

extern "C" void kernel_launch(void* const* d_in, const int* in_sizes, int n_in,
                              void* d_out, int out_size, void* d_ws, size_t ws_size,
                              hipStream_t stream) {
  const float* q        = (const float*)d_in[0];
  const float* k        = (const float*)d_in[1];
  const float* v        = (const float*)d_in[2];
  const float* residual = (const float*)d_in[3];
  const float* wo       = (const float*)d_in[4];
  const float* bo       = (const float*)d_in[5];
  float* out = (float*)d_out;

  const size_t QN = (size_t)BATCH * NHEADS * SEQ * DHEAD;  // 4 Mi elems
  unsigned short* qbuf = (unsigned short*)d_ws;
  unsigned short* kbuf = qbuf + QN;
  unsigned short* vtb  = qbuf + 2 * QN;
  unsigned short* wtb  = qbuf + 3 * QN;
  unsigned short* zb   = qbuf + 3 * QN + (size_t)DMODEL * DMODEL;

  prep_kernel<<<dim3(6400), 256, 0, stream>>>(
      q, k, v, wo, residual, qbuf, kbuf, vtb, wtb,
      out + (size_t)BATCH * SEQ * DMODEL);
  attn_kernel<<<dim3(512), 256, 0, stream>>>(qbuf, kbuf, vtb, zb);
  proj_kernel<<<dim3(BATCH * SEQ / 128, DMODEL / 64), 256, 0, stream>>>(zb, wtb, bo, out);
}